// Round 4
// baseline (346.127 us; speedup 1.0000x reference)
//
#include <hip/hip_runtime.h>
#include <math.h>

// VQ-VAE VectorQuantizer: B=32,T=2048,D=64,K=1024  -> N=65536 rows.
// Outputs (flat f32 in d_out): quantized_st [N*64], indices [N], vq_loss,
// e_latent_loss, codebook_loss.
//
// Round 4: TRANSPOSED argmin (lanes = codes, GEMM-style register tile).
// Rounds 1-3 (lanes = rows, embedding via scalar path) were pinned at 170us
// (VALUBusy 73%) across three different loop structures -> the scheme itself
// was the bottleneck. New scheme per wave: 8 rows x 1024 codes, acc[8];
// per d: 1 coalesced e_T vector load + 1 uniform 32B x_T load (readfirstlane
// -> s_load) + 8 FMAs. Exact numpy semantics preserved:
//  - per (row,code): sequential d=0..63 fmaf chain (same values, same order)
//  - T = fl(sx+se_j); dist = fmaf(-2,acc,T)  (bit-identical to rounds 1-3)
//  - argmin: per-lane strict-< ascending j, cross-lane u64 min over
//    (monotone_float_key<<32)|j  == numpy first-min
//  - sx/se: numpy pairwise 8-accumulator pattern (verified absmax 0.0)
// Workspace-guarded: needs ~17 MB (x_T); falls back to round-3 path else.

namespace {
constexpr int NROWS  = 65536;
constexpr int DDIM   = 64;
constexpr int KCODES = 1024;
constexpr int RPW    = 8;                 // rows per wave
constexpr int NCHUNK = KCODES / 64;       // 16 code-chunks of 64 lanes

// ---- main-path ws layout (bytes)
constexpr size_t WS_LOSS = 0;                                  // double
constexpr size_t WS_SE   = 256;                                // float[K]
constexpr size_t WS_SX   = 8192;                               // float[N]
constexpr size_t WS_ET   = WS_SX + (size_t)NROWS * 4;          // float[64*1024]
constexpr size_t WS_XT   = WS_ET + (size_t)DDIM * KCODES * 4;  // float[64*65536]
constexpr size_t WS_BIDX = WS_XT + (size_t)DDIM * NROWS * 4;   // int[N]
constexpr size_t WS_NEED = WS_BIDX + (size_t)NROWS * 4;        // ~17.6 MB

// ---- fallback (round-3) ws layout
constexpr int KPART = 4;
constexpr int CPP = KCODES / KPART;
constexpr size_t FB_BVAL = 8192;
constexpr size_t FB_BIDX = FB_BVAL + (size_t)KPART * NROWS * 4;
}

// ---------------- prep: se[j] (numpy pairwise), e_T transpose, zero loss
__global__ __launch_bounds__(256) void vq_prep_e(const float* __restrict__ emb,
                                                 float* __restrict__ se,
                                                 float* __restrict__ e_t,
                                                 double* __restrict__ loss_accum) {
  #pragma clang fp contract(off)
  const int t = blockIdx.x * 256 + threadIdx.x;
  if (t == 0 && blockIdx.x == 0) *loss_accum = 0.0;
  if (t < KCODES) {
    const float* e = emb + (size_t)t * DDIM;
    float r[8];
    #pragma unroll
    for (int j = 0; j < 8; ++j) r[j] = e[j] * e[j];
    #pragma unroll
    for (int i = 8; i < DDIM; i += 8) {
      #pragma unroll
      for (int j = 0; j < 8; ++j) r[j] += e[i + j] * e[i + j];
    }
    se[t] = ((r[0] + r[1]) + (r[2] + r[3])) + ((r[4] + r[5]) + (r[6] + r[7]));
    #pragma unroll
    for (int d = 0; d < DDIM; ++d) e_t[(size_t)d * KCODES + t] = e[d];
  }
}

// ---------------- x -> x_T tiled transpose (coalesced both sides)
__global__ __launch_bounds__(256) void vq_xt(const float* __restrict__ x,
                                             float* __restrict__ x_t) {
  __shared__ float tile[64][65];
  const int tid = threadIdx.x;
  const int rowbase = blockIdx.x * 64;
  #pragma unroll
  for (int i = 0; i < 16; ++i) {
    const int idx = i * 256 + tid;
    const int r = idx >> 6, d = idx & 63;
    tile[r][d] = x[(size_t)(rowbase + r) * DDIM + d];
  }
  __syncthreads();
  #pragma unroll
  for (int i = 0; i < 16; ++i) {
    const int idx = i * 256 + tid;
    const int d = idx >> 6, r = idx & 63;
    x_t[(size_t)d * NROWS + rowbase + r] = tile[r][d];
  }
}

// ---------------- sx[r] = ||x_r||^2, numpy pairwise, from x_T (coalesced)
__global__ __launch_bounds__(256) void vq_sx(const float* __restrict__ x_t,
                                             float* __restrict__ sx) {
  #pragma clang fp contract(off)
  const int r = blockIdx.x * 256 + threadIdx.x;
  float a[8];
  #pragma unroll
  for (int j = 0; j < 8; ++j) {
    const float v = x_t[(size_t)j * NROWS + r];
    a[j] = v * v;
  }
  #pragma unroll
  for (int i = 8; i < DDIM; i += 8) {
    #pragma unroll
    for (int j = 0; j < 8; ++j) {
      const float v = x_t[(size_t)(i + j) * NROWS + r];
      a[j] += v * v;
    }
  }
  sx[r] = ((a[0] + a[1]) + (a[2] + a[3])) + ((a[4] + a[5]) + (a[6] + a[7]));
}

// ---------------- main: transposed argmin. wave = 8 rows x 1024 codes.
__global__ __launch_bounds__(256) void vq_argmin_t(const float* __restrict__ x_t,
                                                   const float* __restrict__ e_t,
                                                   const float* __restrict__ se,
                                                   const float* __restrict__ sx,
                                                   int* __restrict__ bidx) {
  #pragma clang fp contract(off)
  const int lane = threadIdx.x & 63;
  const int wid  = threadIdx.x >> 6;
  // force wave-uniformity so x/sx loads become scalar loads
  const int rowbase = __builtin_amdgcn_readfirstlane(blockIdx.x * (4 * RPW) + wid * RPW);

  float sxv[RPW];
  #pragma unroll
  for (int r = 0; r < RPW; ++r) sxv[r] = sx[rowbase + r];  // uniform -> s_load

  unsigned long long best[RPW];
  #pragma unroll
  for (int r = 0; r < RPW; ++r) best[r] = ~0ull;

  for (int ck = 0; ck < NCHUNK; ++ck) {
    float acc[RPW];
    #pragma unroll
    for (int r = 0; r < RPW; ++r) acc[r] = 0.0f;

    const float* ecol = e_t + (size_t)ck * 64 + lane;
    #pragma unroll 8
    for (int d = 0; d < DDIM; ++d) {
      const float ev = ecol[(size_t)d * KCODES];             // coalesced 256B/wave
      const float4 xa = *reinterpret_cast<const float4*>(x_t + (size_t)d * NROWS + rowbase);     // uniform
      const float4 xb = *reinterpret_cast<const float4*>(x_t + (size_t)d * NROWS + rowbase + 4); // uniform
      acc[0] = __builtin_fmaf(xa.x, ev, acc[0]);
      acc[1] = __builtin_fmaf(xa.y, ev, acc[1]);
      acc[2] = __builtin_fmaf(xa.z, ev, acc[2]);
      acc[3] = __builtin_fmaf(xa.w, ev, acc[3]);
      acc[4] = __builtin_fmaf(xb.x, ev, acc[4]);
      acc[5] = __builtin_fmaf(xb.y, ev, acc[5]);
      acc[6] = __builtin_fmaf(xb.z, ev, acc[6]);
      acc[7] = __builtin_fmaf(xb.w, ev, acc[7]);
    }

    const float sev = se[ck * 64 + lane];                    // coalesced
    const unsigned int j = (unsigned int)(ck * 64 + lane);
    #pragma unroll
    for (int r = 0; r < RPW; ++r) {
      const float T = sxv[r] + sev;                          // fl(sx + se_j)
      const float dist = __builtin_fmaf(-2.0f, acc[r], T);   // fl(T - 2*acc)
      const unsigned int b = __float_as_uint(dist);
      const unsigned int key = b ^ ((unsigned int)((int)b >> 31) | 0x80000000u);
      const unsigned long long comb = ((unsigned long long)key << 32) | j;
      if (comb < best[r]) best[r] = comb;                    // strict: first-min
    }
  }

  // cross-lane min (ties -> smallest j, in low bits)
  #pragma unroll
  for (int r = 0; r < RPW; ++r) {
    #pragma unroll
    for (int off = 32; off > 0; off >>= 1) {
      const unsigned long long o = __shfl_xor(best[r], off, 64);
      if (o < best[r]) best[r] = o;
    }
  }
  if (lane == 0) {
    #pragma unroll
    for (int r = 0; r < RPW; ++r)
      bidx[rowbase + r] = (int)(best[r] & 0xFFFFFFFFu);
  }
}

// ---------------- finalize (direct bidx): gather, ST output, loss
__global__ __launch_bounds__(256) void vq_finalize1(const float* __restrict__ x,
                                                    const float* __restrict__ emb,
                                                    const int* __restrict__ bidx,
                                                    float* __restrict__ out,
                                                    double* __restrict__ loss_accum) {
  #pragma clang fp contract(off)
  const int row = blockIdx.x * 256 + (int)threadIdx.x;
  const int bi = bidx[row];

  const float* xr = x + (size_t)row * DDIM;
  const float* ep = emb + (size_t)bi * DDIM;
  float* orow = out + (size_t)row * DDIM;
  float lsum = 0.0f;
  #pragma unroll
  for (int d = 0; d < DDIM; ++d) {
    const float xd = xr[d];
    const float q  = ep[d];
    const float diff = q - xd;
    orow[d] = xd + diff;
    lsum += diff * diff;
  }
  out[(size_t)NROWS * DDIM + row] = (float)bi;

  #pragma unroll
  for (int off = 32; off > 0; off >>= 1) lsum += __shfl_down(lsum, off, 64);
  if ((threadIdx.x & 63) == 0) atomicAdd(loss_accum, (double)lsum);
}

// ---------------- scalars
__global__ void vq_scalars(const double* __restrict__ loss_accum,
                           float* __restrict__ out) {
  if (threadIdx.x == 0 && blockIdx.x == 0) {
    const double m = *loss_accum / (double)((size_t)NROWS * DDIM);
    const float el = (float)m;
    float* tail = out + (size_t)NROWS * DDIM + NROWS;
    tail[0] = 0.25f * el;
    tail[1] = el;
    tail[2] = 0.0f;
  }
}

// ================= fallback path (round-3, proven): used if ws too small ====
__global__ __launch_bounds__(256) void vq_prep_fb(const float* __restrict__ emb,
                                                  float* __restrict__ se,
                                                  double* __restrict__ loss_accum) {
  #pragma clang fp contract(off)
  const int t = blockIdx.x * 256 + threadIdx.x;
  if (t == 0 && blockIdx.x == 0) *loss_accum = 0.0;
  if (t < KCODES) {
    const float* e = emb + (size_t)t * DDIM;
    float r[8];
    #pragma unroll
    for (int j = 0; j < 8; ++j) r[j] = e[j] * e[j];
    #pragma unroll
    for (int i = 8; i < DDIM; i += 8) {
      #pragma unroll
      for (int j = 0; j < 8; ++j) r[j] += e[i + j] * e[i + j];
    }
    se[t] = ((r[0] + r[1]) + (r[2] + r[3])) + ((r[4] + r[5]) + (r[6] + r[7]));
  }
}

__global__ __launch_bounds__(256) void vq_argmin_fb(const float* __restrict__ x,
                                                    const float* __restrict__ emb,
                                                    const float* __restrict__ se,
                                                    float* __restrict__ bval,
                                                    int* __restrict__ bidx) {
  #pragma clang fp contract(off)
  const int part = blockIdx.x & (KPART - 1);
  const int row = (blockIdx.x >> 2) * 256 + (int)threadIdx.x;
  const float* xr = x + (size_t)row * DDIM;
  float xv[DDIM];
  #pragma unroll
  for (int d = 0; d < DDIM; d += 4) {
    const float4 v = *reinterpret_cast<const float4*>(xr + d);
    xv[d] = v.x; xv[d + 1] = v.y; xv[d + 2] = v.z; xv[d + 3] = v.w;
  }
  float r[8];
  #pragma unroll
  for (int j = 0; j < 8; ++j) r[j] = xv[j] * xv[j];
  #pragma unroll
  for (int i = 8; i < DDIM; i += 8) {
    #pragma unroll
    for (int j = 0; j < 8; ++j) r[j] += xv[i + j] * xv[i + j];
  }
  const float sx = ((r[0] + r[1]) + (r[2] + r[3])) + ((r[4] + r[5]) + (r[6] + r[7]));
  float best = INFINITY; int bi = 0;
  const int j0 = part * CPP;
  for (int jj = 0; jj < CPP; ++jj) {
    const int j = j0 + jj;
    const float* ep = emb + (size_t)j * DDIM;
    float acc = 0.0f;
    #pragma unroll
    for (int d = 0; d < DDIM; ++d) acc = __builtin_fmaf(xv[d], ep[d], acc);
    const float T = sx + se[j];
    const float dist = __builtin_fmaf(-2.0f, acc, T);
    if (dist < best) { best = dist; bi = j; }
  }
  bval[(size_t)part * NROWS + row] = best;
  bidx[(size_t)part * NROWS + row] = bi;
}

__global__ __launch_bounds__(256) void vq_finalize4(const float* __restrict__ x,
                                                    const float* __restrict__ emb,
                                                    const float* __restrict__ bval,
                                                    const int* __restrict__ bidx,
                                                    float* __restrict__ out,
                                                    double* __restrict__ loss_accum) {
  #pragma clang fp contract(off)
  const int row = blockIdx.x * 256 + (int)threadIdx.x;
  float best = bval[row];
  int   bi   = bidx[row];
  #pragma unroll
  for (int p = 1; p < KPART; ++p) {
    const float v = bval[(size_t)p * NROWS + row];
    const int   i = bidx[(size_t)p * NROWS + row];
    if (v < best) { best = v; bi = i; }
  }
  const float* xr = x + (size_t)row * DDIM;
  const float* ep = emb + (size_t)bi * DDIM;
  float* orow = out + (size_t)row * DDIM;
  float lsum = 0.0f;
  #pragma unroll
  for (int d = 0; d < DDIM; ++d) {
    const float xd = xr[d];
    const float q  = ep[d];
    const float diff = q - xd;
    orow[d] = xd + diff;
    lsum += diff * diff;
  }
  out[(size_t)NROWS * DDIM + row] = (float)bi;
  #pragma unroll
  for (int off = 32; off > 0; off >>= 1) lsum += __shfl_down(lsum, off, 64);
  if ((threadIdx.x & 63) == 0) atomicAdd(loss_accum, (double)lsum);
}

// ============================================================================
extern "C" void kernel_launch(void* const* d_in, const int* in_sizes, int n_in,
                              void* d_out, int out_size, void* d_ws, size_t ws_size,
                              hipStream_t stream) {
  const float* x   = (const float*)d_in[0];  // [N, 64]
  const float* emb = (const float*)d_in[1];  // [K, 64]
  float* out = (float*)d_out;
  char* ws = (char*)d_ws;
  double* loss_accum = (double*)(ws + WS_LOSS);
  float*  se         = (float*)(ws + WS_SE);

  if (ws_size >= WS_NEED) {
    float* sxp = (float*)(ws + WS_SX);
    float* e_t = (float*)(ws + WS_ET);
    float* x_t = (float*)(ws + WS_XT);
    int*   bidx = (int*)(ws + WS_BIDX);

    vq_prep_e<<<KCODES / 256, 256, 0, stream>>>(emb, se, e_t, loss_accum);
    vq_xt<<<NROWS / 64, 256, 0, stream>>>(x, x_t);
    vq_sx<<<NROWS / 256, 256, 0, stream>>>(x_t, sxp);
    vq_argmin_t<<<NROWS / (4 * RPW), 256, 0, stream>>>(x_t, e_t, se, sxp, bidx);
    vq_finalize1<<<NROWS / 256, 256, 0, stream>>>(x, emb, bidx, out, loss_accum);
  } else {
    float* bval = (float*)(ws + FB_BVAL);
    int*   bidx = (int*)(ws + FB_BIDX);
    vq_prep_fb<<<KCODES / 256, 256, 0, stream>>>(emb, se, loss_accum);
    vq_argmin_fb<<<(NROWS / 256) * KPART, 256, 0, stream>>>(x, emb, se, bval, bidx);
    vq_finalize4<<<NROWS / 256, 256, 0, stream>>>(x, emb, bval, bidx, out, loss_accum);
  }
  vq_scalars<<<1, 64, 0, stream>>>(loss_accum, out);
}

// Round 5
// 117.771 us; speedup vs baseline: 2.9390x; 2.9390x over previous
//
#include <hip/hip_runtime.h>
#include <hip/hip_bf16.h>
#include <math.h>

// VQ-VAE VectorQuantizer: B=32,T=2048,D=64,K=1024 -> N=65536 rows.
// Round 5: MFMA (bf16 hi/lo split) distance estimate + rigorous exact rescore.
//   pass1: per-row min m of mfma-dist.  pass2: candidates {d <= m+EPS} ->
//   exact R1-chain rescore -> u64 (dist_bits<<32|j) atomicMin => bitwise equal
//   to the proven rounds-1-3 argmin. Layout self-test + exact fallback kernel
//   guarantee correctness even if the assumed MFMA A/B fragment layout is off.

typedef __attribute__((ext_vector_type(8))) short bf16x8;
typedef __attribute__((ext_vector_type(4))) float f32x4;

namespace {
constexpr int NROWS  = 65536;
constexpr int DDIM   = 64;
constexpr int KCODES = 1024;
constexpr float EPSM = 2e-4f;   // >= 8x the worst-case |d_mfma - d_exact|

// ws layout (bytes) — total ~1.3 MB
constexpr size_t WS_LOSS  = 0;                                // double
constexpr size_t WS_FLAGS = 64;                               // int[2]: layout_ok, overflow
constexpr size_t WS_SE    = 256;                              // float[K]
constexpr size_t WS_SX    = 8192;                             // float[N]
constexpr size_t WS_M     = WS_SX  + (size_t)NROWS * 4;       // float[N]
constexpr size_t WS_KEY   = WS_M   + (size_t)NROWS * 4;       // u64[N]
constexpr size_t WS_EHB   = WS_KEY + (size_t)NROWS * 8;       // bf16[64*2*64*8]
constexpr size_t WS_ELB   = WS_EHB + (size_t)65536 * 2;       // bf16[64*2*64*8]
constexpr size_t WS_NEED  = WS_ELB + (size_t)65536 * 2;
}

__device__ inline short f2bf(float v) {
  __hip_bfloat16 h = __float2bfloat16(v);
  return *reinterpret_cast<short*>(&h);
}
__device__ inline float bf2f(short s) {
  __hip_bfloat16 h;
  *reinterpret_cast<short*>(&h) = s;
  return __bfloat162float(h);
}
__device__ inline f32x4 mfma16(bf16x8 a, bf16x8 b, f32x4 c) {
  return __builtin_amdgcn_mfma_f32_16x16x32_bf16(a, b, c, 0, 0, 0);
}
// asymmetric self-test patterns (transpose-detecting; exact small ints)
__device__ inline float stA(int i, int k) { return (float)(((i * 3 + k) % 7) - 3); }
__device__ inline float stB(int k, int j) { return (float)(((k * 5 + 2 * j) % 11) - 5); }

// ---------------- setup: init, se, sx, e hi/lo pack, MFMA layout self-test
__global__ __launch_bounds__(256) void vq_setup(const float* __restrict__ x,
                                                const float* __restrict__ emb,
                                                float* __restrict__ se,
                                                float* __restrict__ sx,
                                                short* __restrict__ ehB,
                                                short* __restrict__ elB,
                                                unsigned long long* __restrict__ keyBest,
                                                double* __restrict__ loss_accum,
                                                int* __restrict__ flags) {
  #pragma clang fp contract(off)
  const int gid = blockIdx.x * 256 + (int)threadIdx.x;   // grid = 65536 threads

  if (gid == 0) { *loss_accum = 0.0; flags[1] = 0; }
  keyBest[gid] = ~0ull;

  // se[j]: numpy pairwise 8-accumulator (proven absmax 0.0 in R1-R3)
  if (gid < KCODES) {
    const float* e = emb + (size_t)gid * DDIM;
    float r[8];
    #pragma unroll
    for (int j = 0; j < 8; ++j) r[j] = e[j] * e[j];
    #pragma unroll
    for (int i = 8; i < DDIM; i += 8) {
      #pragma unroll
      for (int j = 0; j < 8; ++j) r[j] += e[i + j] * e[i + j];
    }
    se[gid] = ((r[0] + r[1]) + (r[2] + r[3])) + ((r[4] + r[5]) + (r[6] + r[7]));
  }

  // pack eh/el B-fragments: lane l of tile t, chunk dc holds
  // e[t*16+(l&15)][dc*32+(l>>4)*8 + i], i=0..7
  if (gid < 8192) {
    const int t  = gid >> 7;
    const int dc = (gid >> 6) & 1;
    const int l  = gid & 63;
    const int code = t * 16 + (l & 15);
    const int d0   = dc * 32 + (l >> 4) * 8;
    const float* ep = emb + (size_t)code * DDIM + d0;
    const size_t ob = ((size_t)(t * 2 + dc) * 64 + l) * 8;
    #pragma unroll
    for (int i = 0; i < 8; ++i) {
      const float v = ep[i];
      const short h = f2bf(v);
      ehB[ob + i] = h;
      elB[ob + i] = f2bf(v - bf2f(h));
    }
  }

  // sx[row]: numpy pairwise pattern (identical arithmetic to R3's, absmax 0.0)
  {
    const float4* xr4 = reinterpret_cast<const float4*>(x + (size_t)gid * DDIM);
    float r[8];
    {
      const float4 a = xr4[0], b = xr4[1];
      r[0] = a.x * a.x; r[1] = a.y * a.y; r[2] = a.z * a.z; r[3] = a.w * a.w;
      r[4] = b.x * b.x; r[5] = b.y * b.y; r[6] = b.z * b.z; r[7] = b.w * b.w;
    }
    #pragma unroll
    for (int i = 2; i < 16; i += 2) {
      const float4 a = xr4[i], b = xr4[i + 1];
      r[0] += a.x * a.x; r[1] += a.y * a.y; r[2] += a.z * a.z; r[3] += a.w * a.w;
      r[4] += b.x * b.x; r[5] += b.y * b.y; r[6] += b.z * b.z; r[7] += b.w * b.w;
    }
    sx[gid] = ((r[0] + r[1]) + (r[2] + r[3])) + ((r[4] + r[5]) + (r[6] + r[7]));
  }

  // MFMA layout self-test: block 0, wave 0. Validates A, B and C/D mappings.
  if (blockIdx.x == 0 && threadIdx.x < 64) {
    const int l = (int)threadIdx.x;
    bf16x8 a, b;
    #pragma unroll
    for (int i = 0; i < 8; ++i) {
      a[i] = f2bf(stA(l & 15, (l >> 4) * 8 + i));
      b[i] = f2bf(stB((l >> 4) * 8 + i, l & 15));
    }
    f32x4 c = {0.f, 0.f, 0.f, 0.f};
    c = mfma16(a, b, c);
    bool ok = true;
    #pragma unroll
    for (int r = 0; r < 4; ++r) {
      const int row = (l >> 4) * 4 + r, col = l & 15;
      float ref = 0.f;
      for (int k = 0; k < 32; ++k) ref += stA(row, k) * stB(k, col);
      ok = ok && (c[r] == ref);   // exact integer arithmetic — bitwise equal
    }
    const unsigned long long vote = __ballot(ok);
    if (l == 0) flags[0] = (vote == ~0ull) ? 1 : 0;
  }
}

// ---------------- MFMA distance sweep. PASS 1: per-row min. PASS 2: candidates+rescore.
template <int PASS>
__global__ __launch_bounds__(256) void vq_pass(const float* __restrict__ x,
                                               const float* __restrict__ emb,
                                               const short* __restrict__ ehB,
                                               const short* __restrict__ elB,
                                               const float* __restrict__ se,
                                               const float* __restrict__ sx,
                                               float* __restrict__ m,
                                               unsigned long long* __restrict__ keyBest,
                                               int* __restrict__ flags) {
  #pragma clang fp contract(off)
  if (flags[0] == 0) return;   // layout self-test failed -> fallback handles all

  __shared__ unsigned int candList[4][512];
  __shared__ int candCnt[4];

  const int l   = (int)threadIdx.x & 63;
  const int wid = (int)threadIdx.x >> 6;
  const int wbase = blockIdx.x * 64 + wid * 16;   // wave owns 16 rows

  if (PASS == 2 && l == 0) candCnt[wid] = 0;

  // A-fragments: xh/xl for rows wbase..wbase+15 (lane: row=l&15, k=8*(l>>4)+i)
  const float* xp = x + (size_t)(wbase + (l & 15)) * DDIM + (l >> 4) * 8;
  bf16x8 xh[2], xl[2];
  #pragma unroll
  for (int dc = 0; dc < 2; ++dc) {
    const float4 v0 = *reinterpret_cast<const float4*>(xp + dc * 32);
    const float4 v1 = *reinterpret_cast<const float4*>(xp + dc * 32 + 4);
    const float vv[8] = {v0.x, v0.y, v0.z, v0.w, v1.x, v1.y, v1.z, v1.w};
    #pragma unroll
    for (int i = 0; i < 8; ++i) {
      const short h = f2bf(vv[i]);
      xh[dc][i] = h;
      xl[dc][i] = f2bf(vv[i] - bf2f(h));
    }
  }

  const int crow0 = wbase + (l >> 4) * 4;   // this lane's 4 C rows
  float sxv[4], thr[4], minv[4];
  #pragma unroll
  for (int r = 0; r < 4; ++r) {
    sxv[r]  = sx[crow0 + r];
    minv[r] = INFINITY;
    thr[r]  = (PASS == 2) ? (m[crow0 + r] + EPSM) : 0.f;
  }

  for (int t = 0; t < 64; ++t) {
    const bf16x8 eh0 = *reinterpret_cast<const bf16x8*>(ehB + ((size_t)(t * 2 + 0) * 64 + l) * 8);
    const bf16x8 eh1 = *reinterpret_cast<const bf16x8*>(ehB + ((size_t)(t * 2 + 1) * 64 + l) * 8);
    const bf16x8 el0 = *reinterpret_cast<const bf16x8*>(elB + ((size_t)(t * 2 + 0) * 64 + l) * 8);
    const bf16x8 el1 = *reinterpret_cast<const bf16x8*>(elB + ((size_t)(t * 2 + 1) * 64 + l) * 8);
    f32x4 acc = {0.f, 0.f, 0.f, 0.f};
    acc = mfma16(xh[0], eh0, acc);
    acc = mfma16(xh[1], eh1, acc);
    acc = mfma16(xh[0], el0, acc);
    acc = mfma16(xh[1], el1, acc);
    acc = mfma16(xl[0], eh0, acc);
    acc = mfma16(xl[1], eh1, acc);

    const int col = t * 16 + (l & 15);
    const float sev = se[col];
    #pragma unroll
    for (int r = 0; r < 4; ++r) {
      const float T = sxv[r] + sev;                         // == exact-chain T
      const float dist = __builtin_fmaf(-2.0f, acc[r], T);  // mfma estimate
      if (PASS == 1) {
        minv[r] = fminf(minv[r], dist);
      } else if (dist <= thr[r]) {
        const int pos = atomicAdd(&candCnt[wid], 1);
        if (pos < 512)
          candList[wid][pos] = ((unsigned)((l >> 4) * 4 + r) << 16) | (unsigned)col;
      }
    }
  }

  if (PASS == 1) {
    #pragma unroll
    for (int off = 1; off < 16; off <<= 1) {
      #pragma unroll
      for (int r = 0; r < 4; ++r) {
        const float o = __shfl_xor(minv[r], off, 64);
        minv[r] = fminf(minv[r], o);
      }
    }
    if ((l & 15) == 0) {
      #pragma unroll
      for (int r = 0; r < 4; ++r) m[crow0 + r] = minv[r];
    }
  } else {
    int cnt = candCnt[wid];
    if (cnt > 512) { if (l == 0) flags[1] = 1; cnt = 512; }  // -> fallback
    for (int c = l; c < cnt; c += 64) {
      const unsigned int en = candList[wid][c];
      const int rl  = (int)(en >> 16);
      const int col = (int)(en & 0xffffu);
      const int grow = wbase + rl;
      // exact rescore: R1's proven chain (sequential fmaf d=0..63)
      const float* xr = x + (size_t)grow * DDIM;
      const float* ep = emb + (size_t)col * DDIM;
      float acc = 0.0f;
      #pragma unroll
      for (int q = 0; q < 16; ++q) {
        const float4 xv = *reinterpret_cast<const float4*>(xr + q * 4);
        const float4 ev = *reinterpret_cast<const float4*>(ep + q * 4);
        acc = __builtin_fmaf(xv.x, ev.x, acc);
        acc = __builtin_fmaf(xv.y, ev.y, acc);
        acc = __builtin_fmaf(xv.z, ev.z, acc);
        acc = __builtin_fmaf(xv.w, ev.w, acc);
      }
      const float T = sx[grow] + se[col];
      const float dist = __builtin_fmaf(-2.0f, acc, T);
      const unsigned long long key =
          ((unsigned long long)__float_as_uint(dist) << 32) | (unsigned)col;
      atomicMin(&keyBest[grow], key);   // (dist asc, then j asc) == first-min
    }
  }
}

// ---------------- exact fallback (R1-proven loop). Early-exits when MFMA path OK.
__global__ __launch_bounds__(256) void vq_fallback(const float* __restrict__ x,
                                                   const float* __restrict__ emb,
                                                   const float* __restrict__ se,
                                                   const float* __restrict__ sx,
                                                   unsigned long long* __restrict__ keyBest,
                                                   const int* __restrict__ flags) {
  #pragma clang fp contract(off)
  if (flags[0] == 1 && flags[1] == 0) return;
  const int part = blockIdx.x & 3;
  const int row  = (blockIdx.x >> 2) * 256 + (int)threadIdx.x;
  const float* xr = x + (size_t)row * DDIM;
  float xv[DDIM];
  #pragma unroll
  for (int d = 0; d < DDIM; d += 4) {
    const float4 v = *reinterpret_cast<const float4*>(xr + d);
    xv[d] = v.x; xv[d + 1] = v.y; xv[d + 2] = v.z; xv[d + 3] = v.w;
  }
  const float sxv = sx[row];
  float best = INFINITY; int bi = part * 256;
  for (int jj = 0; jj < 256; ++jj) {
    const int j = part * 256 + jj;
    const float* ep = emb + (size_t)j * DDIM;
    float acc = 0.0f;
    #pragma unroll
    for (int d = 0; d < DDIM; ++d) acc = __builtin_fmaf(xv[d], ep[d], acc);
    const float T = sxv + se[j];
    const float dist = __builtin_fmaf(-2.0f, acc, T);
    if (dist < best) { best = dist; bi = j; }
  }
  const unsigned long long key =
      ((unsigned long long)__float_as_uint(best) << 32) | (unsigned)bi;
  atomicMin(&keyBest[row], key);
}

// ---------------- finalize: gather, straight-through out, index, loss
__global__ __launch_bounds__(256) void vq_finalize_key(const float* __restrict__ x,
                                                       const float* __restrict__ emb,
                                                       const unsigned long long* __restrict__ keyBest,
                                                       float* __restrict__ out,
                                                       double* __restrict__ loss_accum) {
  #pragma clang fp contract(off)
  const int row = blockIdx.x * 256 + (int)threadIdx.x;
  const int bi = (int)(keyBest[row] & 0xffffffffull);

  const float* xr = x + (size_t)row * DDIM;
  const float* ep = emb + (size_t)bi * DDIM;
  float* orow = out + (size_t)row * DDIM;
  float lsum = 0.0f;
  #pragma unroll
  for (int d = 0; d < DDIM; ++d) {
    const float xd = xr[d];
    const float q  = ep[d];
    const float diff = q - xd;
    orow[d] = xd + diff;
    lsum += diff * diff;
  }
  out[(size_t)NROWS * DDIM + row] = (float)bi;

  #pragma unroll
  for (int off = 32; off > 0; off >>= 1) lsum += __shfl_down(lsum, off, 64);
  if ((threadIdx.x & 63) == 0) atomicAdd(loss_accum, (double)lsum);
}

// ---------------- scalars
__global__ void vq_scalars(const double* __restrict__ loss_accum,
                           float* __restrict__ out) {
  if (threadIdx.x == 0 && blockIdx.x == 0) {
    const double mm = *loss_accum / (double)((size_t)NROWS * DDIM);
    const float el = (float)mm;
    float* tail = out + (size_t)NROWS * DDIM + NROWS;
    tail[0] = 0.25f * el;
    tail[1] = el;
    tail[2] = 0.0f;
  }
}

// ============================================================================
extern "C" void kernel_launch(void* const* d_in, const int* in_sizes, int n_in,
                              void* d_out, int out_size, void* d_ws, size_t ws_size,
                              hipStream_t stream) {
  const float* x   = (const float*)d_in[0];  // [N, 64]
  const float* emb = (const float*)d_in[1];  // [K, 64]
  float* out = (float*)d_out;
  char* ws = (char*)d_ws;

  double* loss_accum = (double*)(ws + WS_LOSS);
  int*    flags      = (int*)(ws + WS_FLAGS);
  float*  se         = (float*)(ws + WS_SE);
  float*  sxp        = (float*)(ws + WS_SX);
  float*  mbuf       = (float*)(ws + WS_M);
  unsigned long long* keyBest = (unsigned long long*)(ws + WS_KEY);
  short*  ehB        = (short*)(ws + WS_EHB);
  short*  elB        = (short*)(ws + WS_ELB);

  vq_setup<<<NROWS / 256, 256, 0, stream>>>(x, emb, se, sxp, ehB, elB,
                                            keyBest, loss_accum, flags);
  vq_pass<1><<<NROWS / 64, 256, 0, stream>>>(x, emb, ehB, elB, se, sxp,
                                             mbuf, keyBest, flags);
  vq_pass<2><<<NROWS / 64, 256, 0, stream>>>(x, emb, ehB, elB, se, sxp,
                                             mbuf, keyBest, flags);
  vq_fallback<<<(NROWS / 256) * 4, 256, 0, stream>>>(x, emb, se, sxp,
                                                     keyBest, flags);
  vq_finalize_key<<<NROWS / 256, 256, 0, stream>>>(x, emb, keyBest, out,
                                                   loss_accum);
  vq_scalars<<<1, 64, 0, stream>>>(loss_accum, out);
}